// Round 4
// baseline (10299.691 us; speedup 1.0000x reference)
//
#include <hip/hip_runtime.h>

#define TT 1024
#define BB 256
#define CC 41

__device__ __forceinline__ float sigf(float x) {
    float t = __builtin_amdgcn_exp2f(-1.4426950408889634f * x);
    return __builtin_amdgcn_rcpf(1.0f + t);
}
__device__ __forceinline__ float tanhf_fast(float x) {
    float t = __builtin_amdgcn_exp2f(2.8853900817779268f * x);
    return fmaf(-2.0f, __builtin_amdgcn_rcpf(t + 1.0f), 1.0f);
}
__device__ __forceinline__ float lane_bcast(float v, int k) {
    return __uint_as_float(__builtin_amdgcn_readlane(__float_as_uint(v), k));
}

// ---------------------------------------------------------------------------
// Phase GEMM: slab[r, s, gate] = A[r, t(s), :] @ W[dir]^T + bias[dir]
// t(s) = phase*PS + s (fwd) or TT-1-phase*PS-s (bwd).
// A is given as two half-pointers (k<64 from A0 stride sA0; k>=64 from A1
// stride sA1) when SPLIT; else single pointer A0/sA0 (layer 0, K=39).
// Tile: 128 tile-rows (128/PS sequences x PS steps) x 128 gate-cols.
// ---------------------------------------------------------------------------
template <int PS, bool SPLIT>
__global__ __launch_bounds__(256, 2) void gemm_phase(
    const float* __restrict__ A0, int sA0,
    const float* __restrict__ A1, int sA1,
    const float* __restrict__ W,     // [2,256,K]
    const float* __restrict__ bias,  // [2,256]
    float* __restrict__ slab, size_t slabDirStride,
    int K, int phase, int dir_base)
{
    __shared__ float As[32][132];
    __shared__ float Bs[32][132];
    const int tid = threadIdx.x;
    const int bx = blockIdx.x;
    const int n0 = blockIdx.y * 128;
    const int dir = dir_base + blockIdx.z;
    const int tb = dir ? (TT - 1 - phase * PS) : (phase * PS);
    const float* Wd = W + (size_t)dir * 256 * K;
    const float* bd = bias + dir * 256;
    float* slabD = slab + slabDirStride * blockIdx.z;

    const int ty = tid >> 4, tx = tid & 15;
    float acc[8][8];
#pragma unroll
    for (int i = 0; i < 8; ++i)
#pragma unroll
        for (int j = 0; j < 8; ++j) acc[i][j] = 0.f;

    for (int k0 = 0; k0 < K; k0 += 32) {
        const int kc = (K - k0 < 32) ? (K - k0) : 32;
        // ---- stage A ----
        if (SPLIT) {
            const bool hi = (k0 >= 64);
            const float* base = hi ? A1 : A0;
            const int str = hi ? sA1 : sA0;
            const int ko = k0 - (hi ? 64 : 0);
#pragma unroll
            for (int q = 0; q < 4; ++q) {
                const int lin = tid + q * 256;
                const int m = lin >> 3, c4 = lin & 7;
                const int r = bx * (128 / PS) + m / PS;
                const int s = m % PS;
                const int t = dir ? (tb - s) : (tb + s);
                const float4 v =
                    *(const float4*)(base + (size_t)(r * TT + t) * str + ko + c4 * 4);
                As[c4 * 4 + 0][m] = v.x; As[c4 * 4 + 1][m] = v.y;
                As[c4 * 4 + 2][m] = v.z; As[c4 * 4 + 3][m] = v.w;
            }
        } else if (kc == 32) {
#pragma unroll
            for (int q = 0; q < 16; ++q) {
                const int lin = tid + q * 256;
                const int m = lin >> 5, cc = lin & 31;
                const int r = bx * (128 / PS) + m / PS;
                const int s = m % PS;
                const int t = dir ? (tb - s) : (tb + s);
                As[cc][m] = A0[(size_t)(r * TT + t) * sA0 + k0 + cc];
            }
        } else {
            for (int lin = tid; lin < 128 * kc; lin += 256) {
                const int m = lin / kc, cc = lin - m * kc;
                const int r = bx * (128 / PS) + m / PS;
                const int s = m % PS;
                const int t = dir ? (tb - s) : (tb + s);
                As[cc][m] = A0[(size_t)(r * TT + t) * sA0 + k0 + cc];
            }
        }
        // ---- stage W ----
        if (kc == 32) {
#pragma unroll
            for (int q = 0; q < 16; ++q) {
                const int lin = tid + q * 256;
                const int n = lin >> 5, cc = lin & 31;
                Bs[cc][n] = Wd[(size_t)(n0 + n) * K + k0 + cc];
            }
        } else {
            for (int lin = tid; lin < 128 * kc; lin += 256) {
                const int n = lin / kc, cc = lin - n * kc;
                Bs[cc][n] = Wd[(size_t)(n0 + n) * K + k0 + cc];
            }
        }
        __syncthreads();

        for (int kk = 0; kk < kc; ++kk) {
            float a[8], b[8];
            *(float4*)&a[0] = *(const float4*)&As[kk][ty * 4];
            *(float4*)&a[4] = *(const float4*)&As[kk][64 + ty * 4];
            *(float4*)&b[0] = *(const float4*)&Bs[kk][tx * 4];
            *(float4*)&b[4] = *(const float4*)&Bs[kk][64 + tx * 4];
#pragma unroll
            for (int i = 0; i < 8; ++i)
#pragma unroll
                for (int j = 0; j < 8; ++j)
                    acc[i][j] = fmaf(a[i], b[j], acc[i][j]);
        }
        __syncthreads();
    }

    float b0[4], b1[4];
#pragma unroll
    for (int j = 0; j < 4; ++j) {
        b0[j] = bd[n0 + tx * 4 + j];
        b1[j] = bd[n0 + 64 + tx * 4 + j];
    }
#pragma unroll
    for (int i = 0; i < 8; ++i) {
        const int m = (i < 4) ? (ty * 4 + i) : (64 + ty * 4 + i - 4);
        const int r = bx * (128 / PS) + m / PS;
        const int s = m % PS;
        float* so_ = slabD + ((size_t)r * PS + s) * 256;
        float4 v0, v1;
        v0.x = acc[i][0] + b0[0]; v0.y = acc[i][1] + b0[1];
        v0.z = acc[i][2] + b0[2]; v0.w = acc[i][3] + b0[3];
        v1.x = acc[i][4] + b1[0]; v1.y = acc[i][5] + b1[1];
        v1.z = acc[i][6] + b1[2]; v1.w = acc[i][7] + b1[3];
        *(float4*)&so_[n0 + tx * 4] = v0;
        *(float4*)&so_[n0 + 64 + tx * 4] = v1;
    }
}

// ---------------------------------------------------------------------------
// Recurrence: one WAVE per (row, dir). Lane j owns h_j, c_j and w_hh rows
// {j, 64+j, 128+j, 192+j} in VGPRs (launch_bounds(64,1): 512-reg budget).
// h broadcast via readlane; no LDS, no barriers. s-loop unrolled x4 so the
// prefetch slot index is compile-time (no dynamic reg indexing).
// ---------------------------------------------------------------------------
template <int PS>
__global__ __launch_bounds__(64, 1) void recur_phase(
    const float* __restrict__ slab, size_t slabDirStride,
    const float* __restrict__ w_hh,  // [2,256,64]
    float* __restrict__ outF, int strF,
    float* __restrict__ outB, int strB,
    float* __restrict__ state,       // [2,256,128] = {h[64],c[64]}
    int phase, int dir_base)
{
    const int r = blockIdx.x;
    const int dir = dir_base + blockIdx.y;
    const int j = threadIdx.x;

    float wi[64], wf[64], wg[64], wo[64];
    const float* wb = w_hh + (size_t)dir * 256 * 64;
#pragma unroll
    for (int q = 0; q < 16; ++q) {
        float4 v;
        v = *(const float4*)&wb[(size_t)j * 64 + q * 4];
        wi[q * 4] = v.x; wi[q * 4 + 1] = v.y; wi[q * 4 + 2] = v.z; wi[q * 4 + 3] = v.w;
        v = *(const float4*)&wb[(size_t)(64 + j) * 64 + q * 4];
        wf[q * 4] = v.x; wf[q * 4 + 1] = v.y; wf[q * 4 + 2] = v.z; wf[q * 4 + 3] = v.w;
        v = *(const float4*)&wb[(size_t)(128 + j) * 64 + q * 4];
        wg[q * 4] = v.x; wg[q * 4 + 1] = v.y; wg[q * 4 + 2] = v.z; wg[q * 4 + 3] = v.w;
        v = *(const float4*)&wb[(size_t)(192 + j) * 64 + q * 4];
        wo[q * 4] = v.x; wo[q * 4 + 1] = v.y; wo[q * 4 + 2] = v.z; wo[q * 4 + 3] = v.w;
    }

    float* stp = state + ((size_t)dir * 256 + r) * 128 + j;
    float h = 0.f, c = 0.f;
    if (phase != 0) { h = stp[0]; c = stp[64]; }

    const float* gx = slab + slabDirStride * blockIdx.y + (size_t)r * PS * 256 + j;
    const int tb = dir ? (TT - 1 - phase * PS) : (phase * PS);
    float* out = dir ? outB : outF;
    const int str = dir ? strB : strF;
    const ptrdiff_t hstep = dir ? -(ptrdiff_t)str : (ptrdiff_t)str;
    float* hp = out + (size_t)(r * TT + tb) * str + j;

    float pg[4][4];
#pragma unroll
    for (int p = 0; p < 4; ++p) {
        const float* g0 = gx + (size_t)p * 256;
        pg[p][0] = g0[0]; pg[p][1] = g0[64]; pg[p][2] = g0[128]; pg[p][3] = g0[192];
    }

#pragma unroll 1
    for (int s4 = 0; s4 < PS; s4 += 4) {
#pragma unroll
        for (int u = 0; u < 4; ++u) {
            const int s = s4 + u;
            float ai = pg[u][0], af = pg[u][1], ag = pg[u][2], ao = pg[u][3];
            if (s + 4 < PS) {
                const float* gn = gx + (size_t)(s + 4) * 256;
                pg[u][0] = gn[0]; pg[u][1] = gn[64];
                pg[u][2] = gn[128]; pg[u][3] = gn[192];
            }
#pragma unroll
            for (int k = 0; k < 64; ++k) {
                const float hk = lane_bcast(h, k);
                ai = fmaf(hk, wi[k], ai);
                af = fmaf(hk, wf[k], af);
                ag = fmaf(hk, wg[k], ag);
                ao = fmaf(hk, wo[k], ao);
            }
            const float iv = sigf(ai), fv = sigf(af);
            const float gv = tanhf_fast(ag), ov = sigf(ao);
            c = fmaf(fv, c, iv * gv);
            h = ov * tanhf_fast(c);
            hp[0] = h;
            hp += hstep;
        }
    }
    stp[0] = h; stp[64] = c;
}

// ---------------------------------------------------------------------------
// emissions: feats = [H0 cols0:64 (stride 128) | F (stride 64)];
// e written into H0 cols 64:105 (stride 128).
// ---------------------------------------------------------------------------
__global__ __launch_bounds__(256, 2) void emis_kernel(
    const float* __restrict__ hA,  // H0 (fwd half, stride 128)
    const float* __restrict__ hB,  // F  (bwd half, stride 64)
    const float* __restrict__ lw, const float* __restrict__ lb,
    float* __restrict__ eout)      // H0 + 64 (stride 128)
{
    __shared__ float sf[64 * 132];
    __shared__ float swt[41 * 132];
    const int tid = threadIdx.x;
    const size_t bt0 = (size_t)blockIdx.x * 64;

#pragma unroll
    for (int q = 0; q < 4; ++q) {
        const int idx = tid + q * 256;  // 1024 float4s = 64 rows x 16
        const int row = idx >> 4, c4 = idx & 15;
        *(float4*)&sf[row * 132 + c4 * 4] =
            *(const float4*)&hA[(bt0 + row) * 128 + c4 * 4];
    }
#pragma unroll
    for (int q = 0; q < 4; ++q) {
        const int idx = tid + q * 256;
        const int row = idx >> 4, c4 = idx & 15;
        *(float4*)&sf[row * 132 + 64 + c4 * 4] =
            *(const float4*)&hB[(bt0 + row) * 64 + c4 * 4];
    }
    for (int idx = tid; idx < 41 * 32; idx += 256) {
        const int row = idx >> 5, cc = idx & 31;
        *(float4*)&swt[row * 132 + cc * 4] = ((const float4*)lw)[idx];
    }
    __syncthreads();

    const int btg = tid >> 4;
    const int cg = tid & 15;
    const int c0 = cg * 3;
    float acc[4][3];
#pragma unroll
    for (int i = 0; i < 4; ++i)
#pragma unroll
        for (int j = 0; j < 3; ++j) acc[i][j] = 0.f;

    for (int k = 0; k < 128; k += 4) {
        float4 fv[4], wv[3];
#pragma unroll
        for (int i = 0; i < 4; ++i) fv[i] = *(const float4*)&sf[(btg * 4 + i) * 132 + k];
#pragma unroll
        for (int j = 0; j < 3; ++j) {
            const int c = (c0 + j < CC) ? (c0 + j) : (CC - 1);
            wv[j] = *(const float4*)&swt[c * 132 + k];
        }
#pragma unroll
        for (int i = 0; i < 4; ++i)
#pragma unroll
            for (int j = 0; j < 3; ++j) {
                acc[i][j] = fmaf(fv[i].x, wv[j].x, acc[i][j]);
                acc[i][j] = fmaf(fv[i].y, wv[j].y, acc[i][j]);
                acc[i][j] = fmaf(fv[i].z, wv[j].z, acc[i][j]);
                acc[i][j] = fmaf(fv[i].w, wv[j].w, acc[i][j]);
            }
    }
    __syncthreads();
    float* so = sf;  // reuse as [64*41] staging
#pragma unroll
    for (int i = 0; i < 4; ++i)
#pragma unroll
        for (int j = 0; j < 3; ++j) {
            const int c = c0 + j;
            if (c < CC) so[(btg * 4 + i) * CC + c] = acc[i][j] + lb[c];
        }
    __syncthreads();
    for (int q = tid; q < 64 * CC; q += 256) {
        const int row = q / CC, col = q - row * CC;
        eout[(bt0 + row) * 128 + col] = so[q];
    }
}

// One wave per batch row; score vector in lanes; 41-way argmax via unrolled
// tournament (first-index ties, matching np.argmax); bp in LDS; backtrace.
__global__ __launch_bounds__(64, 1) void viterbi_kernel(
    const float* __restrict__ h0,  // e at h0 + b*TT*128 + 64, stride 128
    const float* __restrict__ st, const float* __restrict__ en,
    const float* __restrict__ tr, int* __restrict__ out)
{
    const int b = blockIdx.x;
    const int lane = threadIdx.x;
    __shared__ unsigned char bp[TT][CC];
    const int c = (lane < CC) ? lane : (CC - 1);
    float trc[CC];
#pragma unroll
    for (int p = 0; p < CC; ++p) trc[p] = tr[p * CC + c];

    const float* eb = h0 + (size_t)b * TT * 128 + 64;
    float sval = st[c] + eb[c];

#pragma unroll 1
    for (int t = 1; t < TT; ++t) {
        const float ecur = eb[(size_t)t * 128 + c];

        float cv[CC];
#pragma unroll
        for (int p = 0; p < CC; ++p) cv[p] = lane_bcast(sval, p) + trc[p];

        float v0[21]; int i0[21];
#pragma unroll
        for (int p = 0; p < 20; ++p) {
            const bool rr = cv[2 * p + 1] > cv[2 * p];
            v0[p] = rr ? cv[2 * p + 1] : cv[2 * p];
            i0[p] = rr ? 2 * p + 1 : 2 * p;
        }
        v0[20] = cv[40]; i0[20] = 40;
        float v1[11]; int i1[11];
#pragma unroll
        for (int p = 0; p < 10; ++p) {
            const bool rr = v0[2 * p + 1] > v0[2 * p];
            v1[p] = rr ? v0[2 * p + 1] : v0[2 * p];
            i1[p] = rr ? i0[2 * p + 1] : i0[2 * p];
        }
        v1[10] = v0[20]; i1[10] = i0[20];
        float v2[6]; int i2[6];
#pragma unroll
        for (int p = 0; p < 5; ++p) {
            const bool rr = v1[2 * p + 1] > v1[2 * p];
            v2[p] = rr ? v1[2 * p + 1] : v1[2 * p];
            i2[p] = rr ? i1[2 * p + 1] : i1[2 * p];
        }
        v2[5] = v1[10]; i2[5] = i1[10];
        float v3[3]; int i3[3];
#pragma unroll
        for (int p = 0; p < 3; ++p) {
            const bool rr = v2[2 * p + 1] > v2[2 * p];
            v3[p] = rr ? v2[2 * p + 1] : v2[2 * p];
            i3[p] = rr ? i2[2 * p + 1] : i2[2 * p];
        }
        const bool r4 = v3[1] > v3[0];
        const float v4 = r4 ? v3[1] : v3[0];
        const int i4 = r4 ? i3[1] : i3[0];
        const bool r5 = v3[2] > v4;
        const float wv = r5 ? v3[2] : v4;
        const int wi_ = r5 ? i3[2] : i4;

        if (lane < CC) bp[t][lane] = (unsigned char)wi_;
        sval = wv + ecur;
    }

    __syncthreads();
    const float NEG = -3.0e38f;
    float fin = (lane < CC) ? sval + en[c] : NEG;
    int idx = lane;
#pragma unroll
    for (int off = 32; off; off >>= 1) {
        const float v2 = __shfl_down(fin, off, 64);
        const int i2 = __shfl_down(idx, off, 64);
        if (v2 > fin || (v2 == fin && i2 < idx)) { fin = v2; idx = i2; }
    }
    int tag = __shfl(idx, 0, 64);
    if (lane == 0) {
        int* ob = out + (size_t)b * TT;
        ob[TT - 1] = tag;
        for (int t = TT - 1; t >= 1; --t) {
            tag = bp[t][tag];
            ob[t - 1] = tag;
        }
    }
}

extern "C" void kernel_launch(void* const* d_in, const int* in_sizes, int n_in,
                              void* d_out, int out_size, void* d_ws, size_t ws_size,
                              hipStream_t stream) {
    const float* x       = (const float*)d_in[0];   // [B,T,39]
    const float* w_ih_l0 = (const float*)d_in[1];   // [2,256,39]
    const float* w_hh_l0 = (const float*)d_in[2];   // [2,256,64]
    const float* b_l0    = (const float*)d_in[3];   // [2,256]
    const float* w_ih_r  = (const float*)d_in[4];   // [2,2,256,128]
    const float* w_hh_r  = (const float*)d_in[5];   // [2,2,256,64]
    const float* b_r     = (const float*)d_in[6];   // [2,2,256]
    const float* lin_w   = (const float*)d_in[7];   // [41,128]
    const float* lin_b   = (const float*)d_in[8];   // [41]
    const float* crf_s   = (const float*)d_in[9];
    const float* crf_e   = (const float*)d_in[10];
    const float* crf_t   = (const float*)d_in[11];  // [41,41]
    int* out = (int*)d_out;

    float* H0    = (float*)d_ws;                     // [B,T,128]  128 MiB
    float* F     = H0 + (size_t)BB * TT * 128;       // [B,T,64]    64 MiB
    float* slab  = F + (size_t)BB * TT * 64;         //             32 MiB
    float* state = slab + (size_t)BB * 128 * 256;    //            256 KiB

    // ---- layer 0: input x (read-only) -> H0[0:64]=fwd, H0[64:128]=bwd.
    // Both dirs concurrent; two PS=64 slabs (16 MiB each).
    const size_t SLAB0 = (size_t)BB * 64 * 256;
    for (int ph = 0; ph < 16; ++ph) {
        gemm_phase<64, false><<<dim3(128, 2, 2), 256, 0, stream>>>(
            x, 39, nullptr, 0, w_ih_l0, b_l0, slab, SLAB0, 39, ph, 0);
        recur_phase<64><<<dim3(256, 2), 64, 0, stream>>>(
            slab, SLAB0, w_hh_l0, H0, 128, H0 + 64, 128, state, ph, 0);
    }

    // ---- layers 1,2: sequential dir sweeps (in-place half-column reuse)
    for (int l = 0; l < 2; ++l) {
        const float* W    = w_ih_r + (size_t)l * 512 * 128;
        const float* bias = b_r + (size_t)l * 512;
        const float* whh  = w_hh_r + (size_t)l * 512 * 64;
        const float* A0   = (l == 0) ? H0 : F;
        const int    s0   = (l == 0) ? 128 : 64;
        const float* A1   = H0 + 64;  const int s1 = 128;
        float* oF = (l == 0) ? F : H0;        const int sF = (l == 0) ? 64 : 128;
        float* oB = (l == 0) ? H0 + 64 : F;   const int sB = (l == 0) ? 128 : 64;
        for (int d = 0; d < 2; ++d) {
            for (int ph = 0; ph < 8; ++ph) {
                gemm_phase<128, true><<<dim3(256, 2, 1), 256, 0, stream>>>(
                    A0, s0, A1, s1, W, bias, slab, 0, 128, ph, d);
                recur_phase<128><<<dim3(256, 1), 64, 0, stream>>>(
                    slab, 0, whh, oF, sF, oB, sB, state, ph, d);
            }
        }
    }

    // ---- emissions into H0[64:105] (dead layer-1 bwd region), then viterbi
    emis_kernel<<<BB * TT / 64, 256, 0, stream>>>(H0, F, lin_w, lin_b, H0 + 64);
    viterbi_kernel<<<BB, 64, 0, stream>>>(H0, crf_s, crf_e, crf_t, out);
}

// Round 5
// 6931.495 us; speedup vs baseline: 1.4859x; 1.4859x over previous
//
#include <hip/hip_runtime.h>

#define TT 1024
#define BB 256
#define CC 41

__device__ __forceinline__ float sigf(float x) {
    float t = __builtin_amdgcn_exp2f(-1.4426950408889634f * x);
    return __builtin_amdgcn_rcpf(1.0f + t);
}
__device__ __forceinline__ float tanhf_fast(float x) {
    float t = __builtin_amdgcn_exp2f(2.8853900817779268f * x);
    return fmaf(-2.0f, __builtin_amdgcn_rcpf(t + 1.0f), 1.0f);
}
__device__ __forceinline__ float lane_bcast(float v, int k) {
    return __uint_as_float(__builtin_amdgcn_readlane(__float_as_uint(v), k));
}

// ---------------------------------------------------------------------------
// Phase GEMM: slab[r, s, gate] = A[r, t(s), :] @ W[dir]^T + bias[dir]
// t(s) = phase*PS + s (fwd) or TT-1-phase*PS-s (bwd).
// A is given as two half-pointers (k<64 from A0 stride sA0; k>=64 from A1
// stride sA1) when SPLIT; else single pointer A0/sA0 (layer 0, K=39).
// Tile: 128 tile-rows (128/PS sequences x PS steps) x 128 gate-cols.
// ---------------------------------------------------------------------------
template <int PS, bool SPLIT>
__global__ __launch_bounds__(256, 2) void gemm_phase(
    const float* __restrict__ A0, int sA0,
    const float* __restrict__ A1, int sA1,
    const float* __restrict__ W,     // [2,256,K]
    const float* __restrict__ bias,  // [2,256]
    float* __restrict__ slab, size_t slabDirStride,
    int K, int phase, int dir_base)
{
    __shared__ float As[32][132];
    __shared__ float Bs[32][132];
    const int tid = threadIdx.x;
    const int bx = blockIdx.x;
    const int n0 = blockIdx.y * 128;
    const int dir = dir_base + blockIdx.z;
    const int tb = dir ? (TT - 1 - phase * PS) : (phase * PS);
    const float* Wd = W + (size_t)dir * 256 * K;
    const float* bd = bias + dir * 256;
    float* slabD = slab + slabDirStride * blockIdx.z;

    const int ty = tid >> 4, tx = tid & 15;
    float acc[8][8];
#pragma unroll
    for (int i = 0; i < 8; ++i)
#pragma unroll
        for (int j = 0; j < 8; ++j) acc[i][j] = 0.f;

    for (int k0 = 0; k0 < K; k0 += 32) {
        const int kc = (K - k0 < 32) ? (K - k0) : 32;
        // ---- stage A ----
        if (SPLIT) {
            const bool hi = (k0 >= 64);
            const float* base = hi ? A1 : A0;
            const int str = hi ? sA1 : sA0;
            const int ko = k0 - (hi ? 64 : 0);
#pragma unroll
            for (int q = 0; q < 4; ++q) {
                const int lin = tid + q * 256;
                const int m = lin >> 3, c4 = lin & 7;
                const int r = bx * (128 / PS) + m / PS;
                const int s = m % PS;
                const int t = dir ? (tb - s) : (tb + s);
                const float4 v =
                    *(const float4*)(base + (size_t)(r * TT + t) * str + ko + c4 * 4);
                As[c4 * 4 + 0][m] = v.x; As[c4 * 4 + 1][m] = v.y;
                As[c4 * 4 + 2][m] = v.z; As[c4 * 4 + 3][m] = v.w;
            }
        } else if (kc == 32) {
#pragma unroll
            for (int q = 0; q < 16; ++q) {
                const int lin = tid + q * 256;
                const int m = lin >> 5, cc = lin & 31;
                const int r = bx * (128 / PS) + m / PS;
                const int s = m % PS;
                const int t = dir ? (tb - s) : (tb + s);
                As[cc][m] = A0[(size_t)(r * TT + t) * sA0 + k0 + cc];
            }
        } else {
            for (int lin = tid; lin < 128 * kc; lin += 256) {
                const int m = lin / kc, cc = lin - m * kc;
                const int r = bx * (128 / PS) + m / PS;
                const int s = m % PS;
                const int t = dir ? (tb - s) : (tb + s);
                As[cc][m] = A0[(size_t)(r * TT + t) * sA0 + k0 + cc];
            }
        }
        // ---- stage W ----
        if (kc == 32) {
#pragma unroll
            for (int q = 0; q < 16; ++q) {
                const int lin = tid + q * 256;
                const int n = lin >> 5, cc = lin & 31;
                Bs[cc][n] = Wd[(size_t)(n0 + n) * K + k0 + cc];
            }
        } else {
            for (int lin = tid; lin < 128 * kc; lin += 256) {
                const int n = lin / kc, cc = lin - n * kc;
                Bs[cc][n] = Wd[(size_t)(n0 + n) * K + k0 + cc];
            }
        }
        __syncthreads();

        for (int kk = 0; kk < kc; ++kk) {
            float a[8], b[8];
            *(float4*)&a[0] = *(const float4*)&As[kk][ty * 4];
            *(float4*)&a[4] = *(const float4*)&As[kk][64 + ty * 4];
            *(float4*)&b[0] = *(const float4*)&Bs[kk][tx * 4];
            *(float4*)&b[4] = *(const float4*)&Bs[kk][64 + tx * 4];
#pragma unroll
            for (int i = 0; i < 8; ++i)
#pragma unroll
                for (int j = 0; j < 8; ++j)
                    acc[i][j] = fmaf(a[i], b[j], acc[i][j]);
        }
        __syncthreads();
    }

    float b0[4], b1[4];
#pragma unroll
    for (int j = 0; j < 4; ++j) {
        b0[j] = bd[n0 + tx * 4 + j];
        b1[j] = bd[n0 + 64 + tx * 4 + j];
    }
#pragma unroll
    for (int i = 0; i < 8; ++i) {
        const int m = (i < 4) ? (ty * 4 + i) : (64 + ty * 4 + i - 4);
        const int r = bx * (128 / PS) + m / PS;
        const int s = m % PS;
        float* so_ = slabD + ((size_t)r * PS + s) * 256;
        float4 v0, v1;
        v0.x = acc[i][0] + b0[0]; v0.y = acc[i][1] + b0[1];
        v0.z = acc[i][2] + b0[2]; v0.w = acc[i][3] + b0[3];
        v1.x = acc[i][4] + b1[0]; v1.y = acc[i][5] + b1[1];
        v1.z = acc[i][6] + b1[2]; v1.w = acc[i][7] + b1[3];
        *(float4*)&so_[n0 + tx * 4] = v0;
        *(float4*)&so_[n0 + 64 + tx * 4] = v1;
    }
}

// ---------------------------------------------------------------------------
// Recurrence: one WAVE per (row, dir). Lane j owns h_j, c_j and w_hh rows
// {j, 64+j, 128+j, 192+j} in VGPRs (launch_bounds(64,1): 512-reg budget).
// h broadcast via readlane; no LDS, no barriers. s-loop unrolled x4 so the
// prefetch slot index is compile-time (no dynamic reg indexing).
// ---------------------------------------------------------------------------
template <int PS>
__global__ __launch_bounds__(64, 1) void recur_phase(
    const float* __restrict__ slab, size_t slabDirStride,
    const float* __restrict__ w_hh,  // [2,256,64]
    float* __restrict__ outF, int strF,
    float* __restrict__ outB, int strB,
    float* __restrict__ state,       // [2,256,128] = {h[64],c[64]}
    int phase, int dir_base)
{
    const int r = blockIdx.x;
    const int dir = dir_base + blockIdx.y;
    const int j = threadIdx.x;

    float wi[64], wf[64], wg[64], wo[64];
    const float* wb = w_hh + (size_t)dir * 256 * 64;
#pragma unroll
    for (int q = 0; q < 16; ++q) {
        float4 v;
        v = *(const float4*)&wb[(size_t)j * 64 + q * 4];
        wi[q * 4] = v.x; wi[q * 4 + 1] = v.y; wi[q * 4 + 2] = v.z; wi[q * 4 + 3] = v.w;
        v = *(const float4*)&wb[(size_t)(64 + j) * 64 + q * 4];
        wf[q * 4] = v.x; wf[q * 4 + 1] = v.y; wf[q * 4 + 2] = v.z; wf[q * 4 + 3] = v.w;
        v = *(const float4*)&wb[(size_t)(128 + j) * 64 + q * 4];
        wg[q * 4] = v.x; wg[q * 4 + 1] = v.y; wg[q * 4 + 2] = v.z; wg[q * 4 + 3] = v.w;
        v = *(const float4*)&wb[(size_t)(192 + j) * 64 + q * 4];
        wo[q * 4] = v.x; wo[q * 4 + 1] = v.y; wo[q * 4 + 2] = v.z; wo[q * 4 + 3] = v.w;
    }

    float* stp = state + ((size_t)dir * 256 + r) * 128 + j;
    float h = 0.f, c = 0.f;
    if (phase != 0) { h = stp[0]; c = stp[64]; }

    const float* gx = slab + slabDirStride * blockIdx.y + (size_t)r * PS * 256 + j;
    const int tb = dir ? (TT - 1 - phase * PS) : (phase * PS);
    float* out = dir ? outB : outF;
    const int str = dir ? strB : strF;
    const ptrdiff_t hstep = dir ? -(ptrdiff_t)str : (ptrdiff_t)str;
    float* hp = out + (size_t)(r * TT + tb) * str + j;

    float pg[4][4];
#pragma unroll
    for (int p = 0; p < 4; ++p) {
        const float* g0 = gx + (size_t)p * 256;
        pg[p][0] = g0[0]; pg[p][1] = g0[64]; pg[p][2] = g0[128]; pg[p][3] = g0[192];
    }

#pragma unroll 1
    for (int s4 = 0; s4 < PS; s4 += 4) {
#pragma unroll
        for (int u = 0; u < 4; ++u) {
            const int s = s4 + u;
            float ai = pg[u][0], af = pg[u][1], ag = pg[u][2], ao = pg[u][3];
            if (s + 4 < PS) {
                const float* gn = gx + (size_t)(s + 4) * 256;
                pg[u][0] = gn[0]; pg[u][1] = gn[64];
                pg[u][2] = gn[128]; pg[u][3] = gn[192];
            }
#pragma unroll
            for (int k = 0; k < 64; ++k) {
                const float hk = lane_bcast(h, k);
                ai = fmaf(hk, wi[k], ai);
                af = fmaf(hk, wf[k], af);
                ag = fmaf(hk, wg[k], ag);
                ao = fmaf(hk, wo[k], ao);
            }
            const float iv = sigf(ai), fv = sigf(af);
            const float gv = tanhf_fast(ag), ov = sigf(ao);
            c = fmaf(fv, c, iv * gv);
            h = ov * tanhf_fast(c);
            hp[0] = h;
            hp += hstep;
        }
    }
    stp[0] = h; stp[64] = c;
}

// ---------------------------------------------------------------------------
// emissions: feats = [H0 cols0:64 (stride 128) | F (stride 64)];
// e written into H0 cols 64:105 (stride 128).
// ---------------------------------------------------------------------------
__global__ __launch_bounds__(256, 2) void emis_kernel(
    const float* __restrict__ hA,  // H0 (fwd half, stride 128)
    const float* __restrict__ hB,  // F  (bwd half, stride 64)
    const float* __restrict__ lw, const float* __restrict__ lb,
    float* __restrict__ eout)      // H0 + 64 (stride 128)
{
    __shared__ float sf[64 * 132];
    __shared__ float swt[41 * 132];
    const int tid = threadIdx.x;
    const size_t bt0 = (size_t)blockIdx.x * 64;

#pragma unroll
    for (int q = 0; q < 4; ++q) {
        const int idx = tid + q * 256;  // 1024 float4s = 64 rows x 16
        const int row = idx >> 4, c4 = idx & 15;
        *(float4*)&sf[row * 132 + c4 * 4] =
            *(const float4*)&hA[(bt0 + row) * 128 + c4 * 4];
    }
#pragma unroll
    for (int q = 0; q < 4; ++q) {
        const int idx = tid + q * 256;
        const int row = idx >> 4, c4 = idx & 15;
        *(float4*)&sf[row * 132 + 64 + c4 * 4] =
            *(const float4*)&hB[(bt0 + row) * 64 + c4 * 4];
    }
    for (int idx = tid; idx < 41 * 32; idx += 256) {
        const int row = idx >> 5, cc = idx & 31;
        *(float4*)&swt[row * 132 + cc * 4] = ((const float4*)lw)[idx];
    }
    __syncthreads();

    const int btg = tid >> 4;
    const int cg = tid & 15;
    const int c0 = cg * 3;
    float acc[4][3];
#pragma unroll
    for (int i = 0; i < 4; ++i)
#pragma unroll
        for (int j = 0; j < 3; ++j) acc[i][j] = 0.f;

    for (int k = 0; k < 128; k += 4) {
        float4 fv[4], wv[3];
#pragma unroll
        for (int i = 0; i < 4; ++i) fv[i] = *(const float4*)&sf[(btg * 4 + i) * 132 + k];
#pragma unroll
        for (int j = 0; j < 3; ++j) {
            const int c = (c0 + j < CC) ? (c0 + j) : (CC - 1);
            wv[j] = *(const float4*)&swt[c * 132 + k];
        }
#pragma unroll
        for (int i = 0; i < 4; ++i)
#pragma unroll
            for (int j = 0; j < 3; ++j) {
                acc[i][j] = fmaf(fv[i].x, wv[j].x, acc[i][j]);
                acc[i][j] = fmaf(fv[i].y, wv[j].y, acc[i][j]);
                acc[i][j] = fmaf(fv[i].z, wv[j].z, acc[i][j]);
                acc[i][j] = fmaf(fv[i].w, wv[j].w, acc[i][j]);
            }
    }
    __syncthreads();
    float* so = sf;  // reuse as [64*41] staging
#pragma unroll
    for (int i = 0; i < 4; ++i)
#pragma unroll
        for (int j = 0; j < 3; ++j) {
            const int c = c0 + j;
            if (c < CC) so[(btg * 4 + i) * CC + c] = acc[i][j] + lb[c];
        }
    __syncthreads();
    for (int q = tid; q < 64 * CC; q += 256) {
        const int row = q / CC, col = q - row * CC;
        eout[(bt0 + row) * 128 + col] = so[q];
    }
}

// ---------------------------------------------------------------------------
// Viterbi v3: one block (128 thr, 2 waves) per batch row.
// Thread (c = tid>>1, half = tid&1): serial strict-> max over 21 predecessors
// (low half p=0..20, high half p=20..40; overlap at 20 is harmless for max).
// Pair-combine via shfl_xor(1); low half wins ties -> exact first-index
// semantics (np.argmax). Score rows double-buffered in LDS; ONE barrier/step.
// bp in LDS; in-kernel backtrace on thread 0.
// ---------------------------------------------------------------------------
__global__ __launch_bounds__(128, 1) void viterbi_kernel(
    const float* __restrict__ h0,  // e at h0 + b*TT*128 + 64, stride 128
    const float* __restrict__ st, const float* __restrict__ en,
    const float* __restrict__ tr, int* __restrict__ out)
{
    const int b = blockIdx.x;
    const int tid = threadIdx.x;
    const int ci = tid >> 1;            // candidate class 0..63
    const int ph = tid & 1;             // predecessor-range half
    const bool valid = (ci < CC);
    const int c = valid ? ci : (CC - 1);
    const int pbase = ph ? 20 : 0;      // halves overlap at p=20

    __shared__ unsigned char bp[TT][CC];
    __shared__ float scp[2][CC];

    float trc[21];
#pragma unroll
    for (int i = 0; i < 21; ++i) trc[i] = tr[(pbase + i) * CC + c];

    const float* eb = h0 + (size_t)b * TT * 128 + 64;
    const float NEG = -3.0e38f;

    if (valid && ph == 0) scp[0][c] = st[c] + eb[c];
    __syncthreads();

#pragma unroll 1
    for (int t = 1; t < TT; ++t) {
        const int cur = (t - 1) & 1, nxt = t & 1;
        const float ecur = eb[(size_t)t * 128 + c];

        float best = NEG;
        int bi = 0;
#pragma unroll
        for (int i = 0; i < 21; ++i) {
            const float v = scp[cur][pbase + i] + trc[i];
            if (v > best) { best = v; bi = pbase + i; }  // first-index ties
        }
        const float ob = __shfl_xor(best, 1, 64);
        const int oi = __shfl_xor(bi, 1, 64);
        float wv; int wi_;
        if (ph == 0) {  // our half is low: we win ties
            const bool hw = (ob > best);
            wv = hw ? ob : best;
            wi_ = hw ? oi : bi;
        } else {        // partner is low: partner wins ties
            const bool lw = !(best > ob);
            wv = lw ? ob : best;
            wi_ = lw ? oi : bi;
        }
        if (valid && ph == 0) {
            bp[t][c] = (unsigned char)wi_;
            scp[nxt][c] = wv + ecur;
        }
        __syncthreads();
    }

    // final argmax over classes (wave 0 only), first-index tie-break
    const int lane = tid & 63;
    float fin = (tid < CC) ? scp[(TT - 1) & 1][lane] + en[lane] : NEG;
    int idx = lane;
#pragma unroll
    for (int off = 32; off; off >>= 1) {
        const float v2 = __shfl_down(fin, off, 64);
        const int i2 = __shfl_down(idx, off, 64);
        if (v2 > fin || (v2 == fin && i2 < idx)) { fin = v2; idx = i2; }
    }
    int tag = __shfl(idx, 0, 64);
    if (tid == 0) {
        int* ob = out + (size_t)b * TT;
        ob[TT - 1] = tag;
        for (int t = TT - 1; t >= 1; --t) {
            tag = bp[t][tag];
            ob[t - 1] = tag;
        }
    }
}

extern "C" void kernel_launch(void* const* d_in, const int* in_sizes, int n_in,
                              void* d_out, int out_size, void* d_ws, size_t ws_size,
                              hipStream_t stream) {
    const float* x       = (const float*)d_in[0];   // [B,T,39]
    const float* w_ih_l0 = (const float*)d_in[1];   // [2,256,39]
    const float* w_hh_l0 = (const float*)d_in[2];   // [2,256,64]
    const float* b_l0    = (const float*)d_in[3];   // [2,256]
    const float* w_ih_r  = (const float*)d_in[4];   // [2,2,256,128]
    const float* w_hh_r  = (const float*)d_in[5];   // [2,2,256,64]
    const float* b_r     = (const float*)d_in[6];   // [2,2,256]
    const float* lin_w   = (const float*)d_in[7];   // [41,128]
    const float* lin_b   = (const float*)d_in[8];   // [41]
    const float* crf_s   = (const float*)d_in[9];
    const float* crf_e   = (const float*)d_in[10];
    const float* crf_t   = (const float*)d_in[11];  // [41,41]
    int* out = (int*)d_out;

    float* H0    = (float*)d_ws;                     // [B,T,128]  128 MiB
    float* F     = H0 + (size_t)BB * TT * 128;       // [B,T,64]    64 MiB
    float* slab  = F + (size_t)BB * TT * 64;         //             32 MiB
    float* state = slab + (size_t)BB * 128 * 256;    //            256 KiB

    // ---- layer 0: input x (read-only) -> H0[0:64]=fwd, H0[64:128]=bwd.
    // Both dirs concurrent; two PS=64 slabs (16 MiB each).
    const size_t SLAB0 = (size_t)BB * 64 * 256;
    for (int ph = 0; ph < 16; ++ph) {
        gemm_phase<64, false><<<dim3(128, 2, 2), 256, 0, stream>>>(
            x, 39, nullptr, 0, w_ih_l0, b_l0, slab, SLAB0, 39, ph, 0);
        recur_phase<64><<<dim3(256, 2), 64, 0, stream>>>(
            slab, SLAB0, w_hh_l0, H0, 128, H0 + 64, 128, state, ph, 0);
    }

    // ---- layers 1,2: sequential dir sweeps (in-place half-column reuse)
    for (int l = 0; l < 2; ++l) {
        const float* W    = w_ih_r + (size_t)l * 512 * 128;
        const float* bias = b_r + (size_t)l * 512;
        const float* whh  = w_hh_r + (size_t)l * 512 * 64;
        const float* A0   = (l == 0) ? H0 : F;
        const int    s0   = (l == 0) ? 128 : 64;
        const float* A1   = H0 + 64;  const int s1 = 128;
        float* oF = (l == 0) ? F : H0;        const int sF = (l == 0) ? 64 : 128;
        float* oB = (l == 0) ? H0 + 64 : F;   const int sB = (l == 0) ? 128 : 64;
        for (int d = 0; d < 2; ++d) {
            for (int ph = 0; ph < 8; ++ph) {
                gemm_phase<128, true><<<dim3(256, 2, 1), 256, 0, stream>>>(
                    A0, s0, A1, s1, W, bias, slab, 0, 128, ph, d);
                recur_phase<128><<<dim3(256, 1), 64, 0, stream>>>(
                    slab, 0, whh, oF, sF, oB, sB, state, ph, d);
            }
        }
    }

    // ---- emissions into H0[64:105] (dead layer-1 bwd region), then viterbi
    emis_kernel<<<BB * TT / 64, 256, 0, stream>>>(H0, F, lin_w, lin_b, H0 + 64);
    viterbi_kernel<<<BB, 128, 0, stream>>>(H0, crf_s, crf_e, crf_t, out);
}

// Round 6
// 6356.862 us; speedup vs baseline: 1.6202x; 1.0904x over previous
//
#include <hip/hip_runtime.h>

#define TT 1024
#define BB 256
#define CC 41

typedef float v2f __attribute__((ext_vector_type(2)));

__device__ __forceinline__ float sigf(float x) {
    float t = __builtin_amdgcn_exp2f(-1.4426950408889634f * x);
    return __builtin_amdgcn_rcpf(1.0f + t);
}
__device__ __forceinline__ float tanhf_fast(float x) {
    float t = __builtin_amdgcn_exp2f(2.8853900817779268f * x);
    return fmaf(-2.0f, __builtin_amdgcn_rcpf(t + 1.0f), 1.0f);
}

// ---------------------------------------------------------------------------
// L0 phase GEMM (K=39, non-split A). slab[r,s,gate] = A[r,t(s),:]@W^T + b.
// ---------------------------------------------------------------------------
template <int PS>
__global__ __launch_bounds__(256, 2) void gemm_l0(
    const float* __restrict__ A0, int sA0,
    const float* __restrict__ W, const float* __restrict__ bias,
    float* __restrict__ slab, size_t slabDirStride,
    int K, int phase)
{
    __shared__ float As[32][132];
    __shared__ float Bs[32][132];
    const int tid = threadIdx.x;
    const int bx = blockIdx.x;
    const int n0 = blockIdx.y * 128;
    const int dir = blockIdx.z;
    const int tb = dir ? (TT - 1 - phase * PS) : (phase * PS);
    const float* Wd = W + (size_t)dir * 256 * K;
    const float* bd = bias + dir * 256;
    float* slabD = slab + slabDirStride * blockIdx.z;

    const int ty = tid >> 4, tx = tid & 15;
    float acc[8][8];
#pragma unroll
    for (int i = 0; i < 8; ++i)
#pragma unroll
        for (int j = 0; j < 8; ++j) acc[i][j] = 0.f;

    for (int k0 = 0; k0 < K; k0 += 32) {
        const int kc = (K - k0 < 32) ? (K - k0) : 32;
        if (kc == 32) {
#pragma unroll
            for (int q = 0; q < 16; ++q) {
                const int lin = tid + q * 256;
                const int m = lin >> 5, cc = lin & 31;
                const int r = bx * (128 / PS) + m / PS;
                const int s = m % PS;
                const int t = dir ? (tb - s) : (tb + s);
                As[cc][m] = A0[(size_t)(r * TT + t) * sA0 + k0 + cc];
            }
#pragma unroll
            for (int q = 0; q < 16; ++q) {
                const int lin = tid + q * 256;
                const int n = lin >> 5, cc = lin & 31;
                Bs[cc][n] = Wd[(size_t)(n0 + n) * K + k0 + cc];
            }
        } else {
            for (int lin = tid; lin < 128 * kc; lin += 256) {
                const int m = lin / kc, cc = lin - m * kc;
                const int r = bx * (128 / PS) + m / PS;
                const int s = m % PS;
                const int t = dir ? (tb - s) : (tb + s);
                As[cc][m] = A0[(size_t)(r * TT + t) * sA0 + k0 + cc];
            }
            for (int lin = tid; lin < 128 * kc; lin += 256) {
                const int n = lin / kc, cc = lin - n * kc;
                Bs[cc][n] = Wd[(size_t)(n0 + n) * K + k0 + cc];
            }
        }
        __syncthreads();
        for (int kk = 0; kk < kc; ++kk) {
            float a[8], b[8];
            *(float4*)&a[0] = *(const float4*)&As[kk][ty * 4];
            *(float4*)&a[4] = *(const float4*)&As[kk][64 + ty * 4];
            *(float4*)&b[0] = *(const float4*)&Bs[kk][tx * 4];
            *(float4*)&b[4] = *(const float4*)&Bs[kk][64 + tx * 4];
#pragma unroll
            for (int i = 0; i < 8; ++i)
#pragma unroll
                for (int j = 0; j < 8; ++j)
                    acc[i][j] = fmaf(a[i], b[j], acc[i][j]);
        }
        __syncthreads();
    }

    float b0[4], b1[4];
#pragma unroll
    for (int j = 0; j < 4; ++j) {
        b0[j] = bd[n0 + tx * 4 + j];
        b1[j] = bd[n0 + 64 + tx * 4 + j];
    }
#pragma unroll
    for (int i = 0; i < 8; ++i) {
        const int m = (i < 4) ? (ty * 4 + i) : (64 + ty * 4 + i - 4);
        const int r = bx * (128 / PS) + m / PS;
        const int s = m % PS;
        float* so_ = slabD + ((size_t)r * PS + s) * 256;
        float4 v0, v1;
        v0.x = acc[i][0] + b0[0]; v0.y = acc[i][1] + b0[1];
        v0.z = acc[i][2] + b0[2]; v0.w = acc[i][3] + b0[3];
        v1.x = acc[i][4] + b1[0]; v1.y = acc[i][5] + b1[1];
        v1.z = acc[i][6] + b1[2]; v1.w = acc[i][7] + b1[3];
        *(float4*)&so_[n0 + tx * 4] = v0;
        *(float4*)&so_[n0 + 64 + tx * 4] = v1;
    }
}

// ---------------------------------------------------------------------------
// L1/L2 phase GEMM, K=128 compile-time, split A halves, register prefetch of
// the next K-chunk issued before the barrier (hides global latency behind
// the previous chunk's compute). PS=128: one sequence x 128 steps per bx.
// ---------------------------------------------------------------------------
__global__ __launch_bounds__(256, 2) void gemm_rec(
    const float* __restrict__ A0, int sA0,   // k<64 half
    const float* __restrict__ A1, int sA1,   // k>=64 half
    const float* __restrict__ W,             // [2,256,128]
    const float* __restrict__ bias,          // [2,256]
    float* __restrict__ slab,
    int phase, int dir)
{
    __shared__ float As[32][132];
    __shared__ float Bs[32][132];
    const int tid = threadIdx.x;
    const int bx = blockIdx.x;               // sequence r
    const int n0 = blockIdx.y * 128;
    const int tb = dir ? (TT - 1 - phase * 128) : (phase * 128);
    const float* Wd = W + (size_t)dir * 256 * 128;
    const float* bd = bias + dir * 256;

    const int ty = tid >> 4, tx = tid & 15;
    const int c4 = tid & 7;
    const int mb = tid >> 3;                 // 0..31

    int rowoff[4];
#pragma unroll
    for (int q = 0; q < 4; ++q) {
        const int s = mb + q * 32;           // step within phase (r==bx, PS=128)
        const int t = dir ? (tb - s) : (tb + s);
        rowoff[q] = bx * TT + t;
    }

    float acc[8][8];
#pragma unroll
    for (int i = 0; i < 8; ++i)
#pragma unroll
        for (int j = 0; j < 8; ++j) acc[i][j] = 0.f;

    float4 ra[4], rb[4];
#pragma unroll
    for (int q = 0; q < 4; ++q)
        ra[q] = *(const float4*)&A0[(size_t)rowoff[q] * sA0 + c4 * 4];
#pragma unroll
    for (int q = 0; q < 4; ++q)
        rb[q] = *(const float4*)&Wd[(size_t)(n0 + mb + q * 32) * 128 + c4 * 4];

#pragma unroll
    for (int ch = 0; ch < 4; ++ch) {
#pragma unroll
        for (int q = 0; q < 4; ++q) {
            const int m = mb + q * 32;
            As[c4 * 4 + 0][m] = ra[q].x; As[c4 * 4 + 1][m] = ra[q].y;
            As[c4 * 4 + 2][m] = ra[q].z; As[c4 * 4 + 3][m] = ra[q].w;
        }
#pragma unroll
        for (int q = 0; q < 4; ++q) {
            const int n = mb + q * 32;
            Bs[c4 * 4 + 0][n] = rb[q].x; Bs[c4 * 4 + 1][n] = rb[q].y;
            Bs[c4 * 4 + 2][n] = rb[q].z; Bs[c4 * 4 + 3][n] = rb[q].w;
        }
        if (ch < 3) {
            const int kn = (ch + 1) * 32;
            const float* base = (kn >= 64) ? A1 : A0;
            const int str = (kn >= 64) ? sA1 : sA0;
            const int ko = kn - ((kn >= 64) ? 64 : 0);
#pragma unroll
            for (int q = 0; q < 4; ++q)
                ra[q] = *(const float4*)&base[(size_t)rowoff[q] * str + ko + c4 * 4];
#pragma unroll
            for (int q = 0; q < 4; ++q)
                rb[q] = *(const float4*)&Wd[(size_t)(n0 + mb + q * 32) * 128 + kn + c4 * 4];
        }
        __syncthreads();
        for (int kk = 0; kk < 32; ++kk) {
            float a[8], b[8];
            *(float4*)&a[0] = *(const float4*)&As[kk][ty * 4];
            *(float4*)&a[4] = *(const float4*)&As[kk][64 + ty * 4];
            *(float4*)&b[0] = *(const float4*)&Bs[kk][tx * 4];
            *(float4*)&b[4] = *(const float4*)&Bs[kk][64 + tx * 4];
#pragma unroll
            for (int i = 0; i < 8; ++i)
#pragma unroll
                for (int j = 0; j < 8; ++j)
                    acc[i][j] = fmaf(a[i], b[j], acc[i][j]);
        }
        __syncthreads();
    }

    float b0[4], b1[4];
#pragma unroll
    for (int j = 0; j < 4; ++j) {
        b0[j] = bd[n0 + tx * 4 + j];
        b1[j] = bd[n0 + 64 + tx * 4 + j];
    }
#pragma unroll
    for (int i = 0; i < 8; ++i) {
        const int s = (i < 4) ? (ty * 4 + i) : (64 + ty * 4 + i - 4);
        float* so_ = slab + ((size_t)bx * 128 + s) * 256;
        float4 v0, v1;
        v0.x = acc[i][0] + b0[0]; v0.y = acc[i][1] + b0[1];
        v0.z = acc[i][2] + b0[2]; v0.w = acc[i][3] + b0[3];
        v1.x = acc[i][4] + b1[0]; v1.y = acc[i][5] + b1[1];
        v1.z = acc[i][6] + b1[2]; v1.w = acc[i][7] + b1[3];
        *(float4*)&so_[n0 + tx * 4] = v0;
        *(float4*)&so_[n0 + 64 + tx * 4] = v1;
    }
}

// ---------------------------------------------------------------------------
// Recurrence: one WAVE per (row, dir). Lane j owns h_j, c_j and w_hh rows
// {j,64+j,128+j,192+j} as float2 pairs (v_pk_fma_f32). h broadcast via LDS
// same-address ds_read_b64 (LDS pipe, overlaps VALU). No barriers.
// ---------------------------------------------------------------------------
template <int PS>
__global__ __launch_bounds__(64, 1) void recur_phase(
    const float* __restrict__ slab, size_t slabDirStride,
    const float* __restrict__ w_hh,  // [2,256,64]
    float* __restrict__ outF, int strF,
    float* __restrict__ outB, int strB,
    float* __restrict__ state,       // [2,256,128] = {h[64],c[64]}
    int phase, int dir_base)
{
    const int r = blockIdx.x;
    const int dir = dir_base + blockIdx.y;
    const int j = threadIdx.x;

    v2f wi[32], wf[32], wg[32], wo[32];
    const float* wb = w_hh + (size_t)dir * 256 * 64;
    const v2f* ri = (const v2f*)&wb[(size_t)j * 64];
    const v2f* rf = (const v2f*)&wb[(size_t)(64 + j) * 64];
    const v2f* rg = (const v2f*)&wb[(size_t)(128 + j) * 64];
    const v2f* ro = (const v2f*)&wb[(size_t)(192 + j) * 64];
#pragma unroll
    for (int q = 0; q < 32; ++q) {
        wi[q] = ri[q]; wf[q] = rf[q]; wg[q] = rg[q]; wo[q] = ro[q];
    }

    __shared__ __align__(16) float hlds[64];
    const v2f* h2 = (const v2f*)hlds;

    float* stp = state + ((size_t)dir * 256 + r) * 128 + j;
    float h = 0.f, c = 0.f;
    if (phase != 0) { h = stp[0]; c = stp[64]; }
    hlds[j] = h;

    const float* gx = slab + slabDirStride * blockIdx.y + (size_t)r * PS * 256 + j;
    const int tb = dir ? (TT - 1 - phase * PS) : (phase * PS);
    float* out = dir ? outB : outF;
    const int str = dir ? strB : strF;
    const ptrdiff_t hstep = dir ? -(ptrdiff_t)str : (ptrdiff_t)str;
    float* hp = out + (size_t)(r * TT + tb) * str + j;

    float pg[4][4];
#pragma unroll
    for (int p = 0; p < 4; ++p) {
        const float* g0 = gx + (size_t)p * 256;
        pg[p][0] = g0[0]; pg[p][1] = g0[64]; pg[p][2] = g0[128]; pg[p][3] = g0[192];
    }

#pragma unroll 1
    for (int s4 = 0; s4 < PS; s4 += 4) {
#pragma unroll
        for (int u = 0; u < 4; ++u) {
            const int s = s4 + u;
            v2f ai2 = {pg[u][0], 0.f}, af2 = {pg[u][1], 0.f};
            v2f ag2 = {pg[u][2], 0.f}, ao2 = {pg[u][3], 0.f};
            if (s + 4 < PS) {
                const float* gn = gx + (size_t)(s + 4) * 256;
                pg[u][0] = gn[0]; pg[u][1] = gn[64];
                pg[u][2] = gn[128]; pg[u][3] = gn[192];
            }
#pragma unroll
            for (int k = 0; k < 32; ++k) {
                const v2f hk = h2[k];   // same-address broadcast ds_read_b64
                ai2 = __builtin_elementwise_fma(hk, wi[k], ai2);
                af2 = __builtin_elementwise_fma(hk, wf[k], af2);
                ag2 = __builtin_elementwise_fma(hk, wg[k], ag2);
                ao2 = __builtin_elementwise_fma(hk, wo[k], ao2);
            }
            const float iv = sigf(ai2.x + ai2.y);
            const float fv = sigf(af2.x + af2.y);
            const float gv = tanhf_fast(ag2.x + ag2.y);
            const float ov = sigf(ao2.x + ao2.y);
            c = fmaf(fv, c, iv * gv);
            h = ov * tanhf_fast(c);
            hlds[j] = h;
            hp[0] = h;
            hp += hstep;
        }
    }
    stp[0] = h; stp[64] = c;
}

// ---------------------------------------------------------------------------
// emissions: feats = [H0 cols0:64 (stride 128) | F (stride 64)];
// e written into H0 cols 64:105 (stride 128).
// ---------------------------------------------------------------------------
__global__ __launch_bounds__(256, 2) void emis_kernel(
    const float* __restrict__ hA, const float* __restrict__ hB,
    const float* __restrict__ lw, const float* __restrict__ lb,
    float* __restrict__ eout)
{
    __shared__ float sf[64 * 132];
    __shared__ float swt[41 * 132];
    const int tid = threadIdx.x;
    const size_t bt0 = (size_t)blockIdx.x * 64;

#pragma unroll
    for (int q = 0; q < 4; ++q) {
        const int idx = tid + q * 256;
        const int row = idx >> 4, p4 = idx & 15;
        *(float4*)&sf[row * 132 + p4 * 4] =
            *(const float4*)&hA[(bt0 + row) * 128 + p4 * 4];
    }
#pragma unroll
    for (int q = 0; q < 4; ++q) {
        const int idx = tid + q * 256;
        const int row = idx >> 4, p4 = idx & 15;
        *(float4*)&sf[row * 132 + 64 + p4 * 4] =
            *(const float4*)&hB[(bt0 + row) * 64 + p4 * 4];
    }
    for (int idx = tid; idx < 41 * 32; idx += 256) {
        const int row = idx >> 5, cc = idx & 31;
        *(float4*)&swt[row * 132 + cc * 4] = ((const float4*)lw)[idx];
    }
    __syncthreads();

    const int btg = tid >> 4;
    const int cg = tid & 15;
    const int c0 = cg * 3;
    float acc[4][3];
#pragma unroll
    for (int i = 0; i < 4; ++i)
#pragma unroll
        for (int j = 0; j < 3; ++j) acc[i][j] = 0.f;

    for (int k = 0; k < 128; k += 4) {
        float4 fv[4], wv[3];
#pragma unroll
        for (int i = 0; i < 4; ++i) fv[i] = *(const float4*)&sf[(btg * 4 + i) * 132 + k];
#pragma unroll
        for (int j = 0; j < 3; ++j) {
            const int c = (c0 + j < CC) ? (c0 + j) : (CC - 1);
            wv[j] = *(const float4*)&swt[c * 132 + k];
        }
#pragma unroll
        for (int i = 0; i < 4; ++i)
#pragma unroll
            for (int j = 0; j < 3; ++j) {
                acc[i][j] = fmaf(fv[i].x, wv[j].x, acc[i][j]);
                acc[i][j] = fmaf(fv[i].y, wv[j].y, acc[i][j]);
                acc[i][j] = fmaf(fv[i].z, wv[j].z, acc[i][j]);
                acc[i][j] = fmaf(fv[i].w, wv[j].w, acc[i][j]);
            }
    }
    __syncthreads();
    float* so = sf;
#pragma unroll
    for (int i = 0; i < 4; ++i)
#pragma unroll
        for (int j = 0; j < 3; ++j) {
            const int c = c0 + j;
            if (c < CC) so[(btg * 4 + i) * CC + c] = acc[i][j] + lb[c];
        }
    __syncthreads();
    for (int q = tid; q < 64 * CC; q += 256) {
        const int row = q / CC, col = q - row * CC;
        eout[(bt0 + row) * 128 + col] = so[q];
    }
}

// ---------------------------------------------------------------------------
// Viterbi v4: round-5 structure (2 waves/row, 21-predecessor halves, exact
// first-index ties) + 8-deep e prefetch ring (compile-time slots) + depth-5
// bracket tree for the 21-way argmax.
// ---------------------------------------------------------------------------
__global__ __launch_bounds__(128, 1) void viterbi_kernel(
    const float* __restrict__ h0,  // e at h0 + b*TT*128 + 64, stride 128
    const float* __restrict__ st, const float* __restrict__ en,
    const float* __restrict__ tr, int* __restrict__ out)
{
    const int b = blockIdx.x;
    const int tid = threadIdx.x;
    const int ci = tid >> 1;
    const int ph = tid & 1;
    const bool valid = (ci < CC);
    const int c = valid ? ci : (CC - 1);
    const int pbase = ph ? 20 : 0;

    __shared__ unsigned char bp[TT][CC];
    __shared__ float scp[2][CC];

    float trc[21];
#pragma unroll
    for (int i = 0; i < 21; ++i) trc[i] = tr[(pbase + i) * CC + c];

    const float* eb = h0 + (size_t)b * TT * 128 + 64;
    if (valid && ph == 0) scp[0][c] = st[c] + eb[c];
    __syncthreads();

    auto vstep = [&](int t, int cur, float ecur) {
        float v[21];
#pragma unroll
        for (int i = 0; i < 21; ++i) v[i] = scp[cur][pbase + i] + trc[i];
        float a1[11]; int x1[11];
#pragma unroll
        for (int i = 0; i < 10; ++i) {
            const bool rr = v[2 * i + 1] > v[2 * i];
            a1[i] = rr ? v[2 * i + 1] : v[2 * i];
            x1[i] = pbase + (rr ? 2 * i + 1 : 2 * i);
        }
        a1[10] = v[20]; x1[10] = pbase + 20;
        float a2[6]; int x2[6];
#pragma unroll
        for (int i = 0; i < 5; ++i) {
            const bool rr = a1[2 * i + 1] > a1[2 * i];
            a2[i] = rr ? a1[2 * i + 1] : a1[2 * i];
            x2[i] = rr ? x1[2 * i + 1] : x1[2 * i];
        }
        a2[5] = a1[10]; x2[5] = x1[10];
        float a3[3]; int x3[3];
#pragma unroll
        for (int i = 0; i < 3; ++i) {
            const bool rr = a3 ? false : false;  // placeholder (overwritten below)
            (void)rr;
            const bool r2 = a2[2 * i + 1] > a2[2 * i];
            a3[i] = r2 ? a2[2 * i + 1] : a2[2 * i];
            x3[i] = r2 ? x2[2 * i + 1] : x2[2 * i];
        }
        const bool r4 = a3[1] > a3[0];
        const float a4 = r4 ? a3[1] : a3[0];
        const int x4 = r4 ? x3[1] : x3[0];
        const bool r5 = a3[2] > a4;
        const float best = r5 ? a3[2] : a4;
        const int bi = r5 ? x3[2] : x4;

        const float ob = __shfl_xor(best, 1, 64);
        const int oi = __shfl_xor(bi, 1, 64);
        float wv; int wi_;
        if (ph == 0) {               // our half is low: we win ties
            const bool hw = (ob > best);
            wv = hw ? ob : best;
            wi_ = hw ? oi : bi;
        } else {                     // partner is low: partner wins ties
            const bool lw = !(best > ob);
            wv = lw ? ob : best;
            wi_ = lw ? oi : bi;
        }
        if (valid && ph == 0) {
            bp[t][c] = (unsigned char)wi_;
            scp[cur ^ 1][c] = wv + ecur;
        }
        __syncthreads();
    };

    float ep[8];
#pragma unroll
    for (int u = 0; u < 8; ++u) ep[u] = eb[(size_t)(1 + u) * 128 + c];

#pragma unroll 1
    for (int tb = 1; tb + 7 < TT; tb += 8) {   // tb odd -> cur = u&1
#pragma unroll
        for (int u = 0; u < 8; ++u) {
            const int t = tb + u;
            vstep(t, u & 1, ep[u]);
            if (t + 8 < TT) ep[u] = eb[(size_t)(t + 8) * 128 + c];
        }
    }
#pragma unroll
    for (int u = 0; u < 7; ++u) {              // t = 1017..1023
        const int t = TT - 7 + u;
        vstep(t, u & 1, ep[u]);
    }

    const float NEG = -3.0e38f;
    const int lane = tid & 63;
    float fin = (tid < CC) ? scp[(TT - 1) & 1][lane] + en[lane] : NEG;
    int idx = lane;
#pragma unroll
    for (int off = 32; off; off >>= 1) {
        const float v2 = __shfl_down(fin, off, 64);
        const int i2 = __shfl_down(idx, off, 64);
        if (v2 > fin || (v2 == fin && i2 < idx)) { fin = v2; idx = i2; }
    }
    int tag = __shfl(idx, 0, 64);
    if (tid == 0) {
        int* ob = out + (size_t)b * TT;
        ob[TT - 1] = tag;
        for (int t = TT - 1; t >= 1; --t) {
            tag = bp[t][tag];
            ob[t - 1] = tag;
        }
    }
}

extern "C" void kernel_launch(void* const* d_in, const int* in_sizes, int n_in,
                              void* d_out, int out_size, void* d_ws, size_t ws_size,
                              hipStream_t stream) {
    const float* x       = (const float*)d_in[0];   // [B,T,39]
    const float* w_ih_l0 = (const float*)d_in[1];   // [2,256,39]
    const float* w_hh_l0 = (const float*)d_in[2];   // [2,256,64]
    const float* b_l0    = (const float*)d_in[3];   // [2,256]
    const float* w_ih_r  = (const float*)d_in[4];   // [2,2,256,128]
    const float* w_hh_r  = (const float*)d_in[5];   // [2,2,256,64]
    const float* b_r     = (const float*)d_in[6];   // [2,2,256]
    const float* lin_w   = (const float*)d_in[7];   // [41,128]
    const float* lin_b   = (const float*)d_in[8];   // [41]
    const float* crf_s   = (const float*)d_in[9];
    const float* crf_e   = (const float*)d_in[10];
    const float* crf_t   = (const float*)d_in[11];  // [41,41]
    int* out = (int*)d_out;

    float* H0    = (float*)d_ws;                       // [B,T,128]  128 MiB
    float* X     = H0 + (size_t)BB * TT * 128;         // 64 MiB: L0 slabs / F
    float* Y     = X + (size_t)BB * TT * 64;           // 32 MiB: L1/2 slab
    float* state = Y + (size_t)BB * 128 * 256;         // 256 KiB

    // ---- layer 0 (K=39): both dirs concurrent, PS=128, 8 phases.
    // slabF = X, slabB = X + 32 MiB. Writes H0[0:64]=fwd, H0[64:128]=bwd.
    const size_t SLAB0 = (size_t)BB * 128 * 256;
    for (int ph = 0; ph < 8; ++ph) {
        gemm_l0<128><<<dim3(BB, 2, 2), 256, 0, stream>>>(
            x, 39, w_ih_l0, b_l0, X, SLAB0, 39, ph);
        recur_phase<128><<<dim3(BB, 2), 64, 0, stream>>>(
            X, SLAB0, w_hh_l0, H0, 128, H0 + 64, 128, state, ph, 0);
    }

    // ---- layers 1,2: sequential dir sweeps (in-place half-column reuse)
    for (int l = 0; l < 2; ++l) {
        const float* W    = w_ih_r + (size_t)l * 512 * 128;
        const float* bias = b_r + (size_t)l * 512;
        const float* whh  = w_hh_r + (size_t)l * 512 * 64;
        const float* A0   = (l == 0) ? H0 : X;
        const int    s0   = (l == 0) ? 128 : 64;
        const float* A1   = H0 + 64;  const int s1 = 128;
        float* oF = (l == 0) ? X : H0;        const int sF = (l == 0) ? 64 : 128;
        float* oB = (l == 0) ? H0 + 64 : X;   const int sB = (l == 0) ? 128 : 64;
        for (int d = 0; d < 2; ++d) {
            for (int ph = 0; ph < 8; ++ph) {
                gemm_rec<<<dim3(BB, 2, 1), 256, 0, stream>>>(
                    A0, s0, A1, s1, W, bias, Y, ph, d);
                recur_phase<128><<<dim3(BB, 1), 64, 0, stream>>>(
                    Y, 0, whh, oF, sF, oB, sB, state, ph, d);
            }
        }
    }

    // ---- emissions into H0[64:105] (dead layer-1 bwd region), then viterbi
    emis_kernel<<<BB * TT / 64, 256, 0, stream>>>(H0, X, lin_w, lin_b, H0 + 64);
    viterbi_kernel<<<BB, 128, 0, stream>>>(H0, crf_s, crf_e, crf_t, out);
}